// Round 1
// baseline (3305.760 us; speedup 1.0000x reference)
//
#include <hip/hip_runtime.h>
#include <hip/hip_bf16.h>

// Problem constants (from reference)
#define BATCH 2
#define SEQ   2048
#define DMODEL 1024
#define NHEAD 16
#define DK    64
#define MTOK  (BATCH * SEQ)      // 4096 rows for the projection GEMMs

// ---------------------------------------------------------------------------
// Kernel 1/3: C[M,N] = A[M,K] @ W[K,N] + bias[N]   (fp32, 64x64 tile, 4x4/thread)
// M=4096, N=1024, K=1024 — all divisible by tile sizes, no bounds checks.
// ---------------------------------------------------------------------------
__global__ __launch_bounds__(256) void gemm_bias_kernel(
    const float* __restrict__ A, const float* __restrict__ W,
    const float* __restrict__ bias, float* __restrict__ C,
    int M, int N, int K)
{
    __shared__ float As[64][17];   // +1 pad breaks bank conflicts on column reads
    __shared__ float Bs[16][64];

    const int tx = threadIdx.x;    // 0..15
    const int ty = threadIdx.y;    // 0..15
    const int t  = ty * 16 + tx;   // 0..255
    const int row0 = blockIdx.y * 64;
    const int col0 = blockIdx.x * 64;

    float acc[4][4];
#pragma unroll
    for (int i = 0; i < 4; i++)
#pragma unroll
        for (int j = 0; j < 4; j++) acc[i][j] = 0.f;

    for (int k0 = 0; k0 < K; k0 += 16) {
        // Stage A tile (64 rows x 16 cols)
#pragma unroll
        for (int it = 0; it < 4; it++) {
            int e = t + 256 * it;          // 0..1023
            int r = e >> 4, c = e & 15;
            As[r][c] = A[(size_t)(row0 + r) * K + k0 + c];
        }
        // Stage B tile (16 rows x 64 cols) — fully coalesced
#pragma unroll
        for (int it = 0; it < 4; it++) {
            int e = t + 256 * it;
            int r = e >> 6, c = e & 63;
            Bs[r][c] = W[(size_t)(k0 + r) * N + col0 + c];
        }
        __syncthreads();

#pragma unroll
        for (int k = 0; k < 16; k++) {
            float a[4], b[4];
#pragma unroll
            for (int i = 0; i < 4; i++) a[i] = As[ty + 16 * i][k];
#pragma unroll
            for (int j = 0; j < 4; j++) b[j] = Bs[k][tx + 16 * j];
#pragma unroll
            for (int i = 0; i < 4; i++)
#pragma unroll
                for (int j = 0; j < 4; j++) acc[i][j] += a[i] * b[j];
        }
        __syncthreads();
    }

#pragma unroll
    for (int i = 0; i < 4; i++) {
        int r = row0 + ty + 16 * i;
#pragma unroll
        for (int j = 0; j < 4; j++) {
            int c = col0 + tx + 16 * j;
            C[(size_t)r * N + c] = acc[i][j] + bias[c];
        }
    }
}

// ---------------------------------------------------------------------------
// Kernel 2: causal attention, online softmax.
// One block (256 threads) per (b, h, query row i). Key tiles of 256.
// Q,K,V are in [B,S,D] layout (head h occupies columns h*DK .. h*DK+63).
// Output ctx written in [B,S,D] layout so the final GEMM consumes it directly.
// ---------------------------------------------------------------------------
__device__ __forceinline__ float block_reduce_max(float v, float* red, int t)
{
#pragma unroll
    for (int off = 32; off > 0; off >>= 1)
        v = fmaxf(v, __shfl_xor(v, off, 64));
    __syncthreads();                       // protect red[] from previous use
    if ((t & 63) == 0) red[t >> 6] = v;
    __syncthreads();
    return fmaxf(fmaxf(red[0], red[1]), fmaxf(red[2], red[3]));
}

__device__ __forceinline__ float block_reduce_sum(float v, float* red, int t)
{
#pragma unroll
    for (int off = 32; off > 0; off >>= 1)
        v += __shfl_xor(v, off, 64);
    __syncthreads();
    if ((t & 63) == 0) red[t >> 6] = v;
    __syncthreads();
    return red[0] + red[1] + red[2] + red[3];
}

__global__ __launch_bounds__(256) void attn_kernel(
    const float* __restrict__ Q, const float* __restrict__ K,
    const float* __restrict__ V, float* __restrict__ O)
{
    __shared__ float sQ[DK];
    __shared__ float p[256];
    __shared__ float red[4];
    __shared__ float sO[4][DK];

    const int t   = threadIdx.x;           // 0..255
    const int idx = blockIdx.x;            // b*H*S + h*S + i  (consecutive i share (b,h) -> K/V hot in L2)
    const int i   = idx & (SEQ - 1);
    const int h   = (idx >> 11) & (NHEAD - 1);
    const int b   = idx >> 15;

    const int d = t & 63;                  // output dim owned by this thread
    const int c = t >> 6;                  // key-chunk (wave) id, 0..3

    const size_t headOff = (size_t)h * DK;
    const float* Qrow = Q + ((size_t)(b * SEQ + i)) * DMODEL + headOff;

    if (t < DK) sQ[t] = Qrow[t];
    __syncthreads();

    float m = -3.0e38f;
    float l = 0.f;
    float o_part = 0.f;

    for (int j0 = 0; j0 <= i; j0 += 256) {
        const int j = j0 + t;
        float s = -3.0e38f;
        if (j <= i) {
            const float4* K4 = (const float4*)(K + ((size_t)(b * SEQ + j)) * DMODEL + headOff);
            float acc = 0.f;
#pragma unroll
            for (int u = 0; u < 16; u++) {
                float4 kk = K4[u];
                acc += sQ[4*u+0]*kk.x + sQ[4*u+1]*kk.y + sQ[4*u+2]*kk.z + sQ[4*u+3]*kk.w;
            }
            s = acc * 0.125f;              // 1/sqrt(64)
        }

        const float tmax = block_reduce_max(s, red, t);
        const float newm = fmaxf(m, tmax);
        const float p_t  = (j <= i) ? expf(s - newm) : 0.f;
        const float tsum = block_reduce_sum(p_t, red, t);
        const float alpha = expf(m - newm);
        l = l * alpha + tsum;
        m = newm;

        p[t] = p_t;
        __syncthreads();

        // accumulate this wave's 64-key chunk into o_part (dim d)
        o_part *= alpha;
        const int cbase = c * 64;
        int jmax = i - j0 - cbase;         // may be negative (chunk fully masked)
        if (jmax > 63) jmax = 63;
        const float* Vbase = V + ((size_t)(b * SEQ + j0 + cbase)) * DMODEL + headOff + d;
        for (int jj = 0; jj <= jmax; jj++) {
            o_part += p[cbase + jj] * Vbase[(size_t)jj * DMODEL];
        }
        __syncthreads();                   // p[] reused next tile
    }

    sO[c][d] = o_part;
    __syncthreads();
    if (t < DK) {
        const float val = (sO[0][t] + sO[1][t] + sO[2][t] + sO[3][t]) / l;
        O[((size_t)(b * SEQ + i)) * DMODEL + headOff + t] = val;
    }
}

// ---------------------------------------------------------------------------
extern "C" void kernel_launch(void* const* d_in, const int* in_sizes, int n_in,
                              void* d_out, int out_size, void* d_ws, size_t ws_size,
                              hipStream_t stream)
{
    const float* q  = (const float*)d_in[0];
    const float* k  = (const float*)d_in[1];
    const float* v  = (const float*)d_in[2];
    // d_in[3] = mask (int32 tril) — causality is applied analytically (j<=i),
    // identical to the reference's -1e9 masked softmax.
    const float* wq = (const float*)d_in[4];
    const float* bq = (const float*)d_in[5];
    const float* wk = (const float*)d_in[6];
    const float* bk = (const float*)d_in[7];
    const float* wv = (const float*)d_in[8];
    const float* bv = (const float*)d_in[9];
    const float* wo = (const float*)d_in[10];
    const float* bo = (const float*)d_in[11];
    float* out = (float*)d_out;

    const size_t mat = (size_t)MTOK * DMODEL;   // 4096*1024 floats = 16 MB
    float* Qb  = (float*)d_ws;
    float* Kb  = Qb + mat;
    float* Vb  = Kb + mat;
    float* CTX = Vb + mat;                      // total 64 MB of ws

    dim3 blk(16, 16);
    dim3 grd(DMODEL / 64, MTOK / 64);           // (16, 64)

    gemm_bias_kernel<<<grd, blk, 0, stream>>>(q, wq, bq, Qb, MTOK, DMODEL, DMODEL);
    gemm_bias_kernel<<<grd, blk, 0, stream>>>(k, wk, bk, Kb, MTOK, DMODEL, DMODEL);
    gemm_bias_kernel<<<grd, blk, 0, stream>>>(v, wv, bv, Vb, MTOK, DMODEL, DMODEL);

    attn_kernel<<<BATCH * NHEAD * SEQ, 256, 0, stream>>>(Qb, Kb, Vb, CTX);

    gemm_bias_kernel<<<grd, blk, 0, stream>>>(CTX, wo, bo, out, MTOK, DMODEL, DMODEL);
}

// Round 2
// 861.262 us; speedup vs baseline: 3.8383x; 3.8383x over previous
//
#include <hip/hip_runtime.h>
#include <hip/hip_bf16.h>

// Problem constants (from reference)
#define BATCH 2
#define SEQ   2048
#define DMODEL 1024
#define NHEAD 16
#define DK    64
#define MTOK  (BATCH * SEQ)      // 4096 rows for the projection GEMMs

typedef __attribute__((ext_vector_type(8))) short bf16x8;   // 8 bf16 in 4 VGPRs
typedef __attribute__((ext_vector_type(4))) float f32x4;    // MFMA 16x16 accumulator

// float -> bf16 bits, round-to-nearest-even (matches HW conversion for our range)
__device__ __forceinline__ unsigned short f2bf(float x) {
    unsigned u = __float_as_uint(x);
    u = (u + 0x7FFFu + ((u >> 16) & 1u)) >> 16;
    return (unsigned short)u;
}

__device__ __forceinline__ void store_out(float* p, float v)          { *p = v; }
__device__ __forceinline__ void store_out(unsigned short* p, float v) { *p = f2bf(v); }

// ---------------------------------------------------------------------------
// C[M,N] = A[M,K] @ W[K,N] + bias[N]   (fp32 compute, 64x64 tile, 4x4/thread)
// OutT = float (final projection) or ushort/bf16-bits (Q/K/V for attention).
// ---------------------------------------------------------------------------
template <typename OutT>
__global__ __launch_bounds__(256) void gemm_bias_kernel(
    const float* __restrict__ A, const float* __restrict__ W,
    const float* __restrict__ bias, OutT* __restrict__ C,
    int M, int N, int K)
{
    __shared__ float As[64][17];   // +1 pad breaks bank conflicts on column reads
    __shared__ float Bs[16][64];

    const int tx = threadIdx.x;    // 0..15
    const int ty = threadIdx.y;    // 0..15
    const int t  = ty * 16 + tx;   // 0..255
    const int row0 = blockIdx.y * 64;
    const int col0 = blockIdx.x * 64;

    float acc[4][4];
#pragma unroll
    for (int i = 0; i < 4; i++)
#pragma unroll
        for (int j = 0; j < 4; j++) acc[i][j] = 0.f;

    for (int k0 = 0; k0 < K; k0 += 16) {
#pragma unroll
        for (int it = 0; it < 4; it++) {
            int e = t + 256 * it;          // 0..1023
            int r = e >> 4, c = e & 15;
            As[r][c] = A[(size_t)(row0 + r) * K + k0 + c];
        }
#pragma unroll
        for (int it = 0; it < 4; it++) {
            int e = t + 256 * it;
            int r = e >> 6, c = e & 63;
            Bs[r][c] = W[(size_t)(k0 + r) * N + col0 + c];
        }
        __syncthreads();

#pragma unroll
        for (int k = 0; k < 16; k++) {
            float a[4], b[4];
#pragma unroll
            for (int i = 0; i < 4; i++) a[i] = As[ty + 16 * i][k];
#pragma unroll
            for (int j = 0; j < 4; j++) b[j] = Bs[k][tx + 16 * j];
#pragma unroll
            for (int i = 0; i < 4; i++)
#pragma unroll
                for (int j = 0; j < 4; j++) acc[i][j] += a[i] * b[j];
        }
        __syncthreads();
    }

#pragma unroll
    for (int i = 0; i < 4; i++) {
        int r = row0 + ty + 16 * i;
#pragma unroll
        for (int j = 0; j < 4; j++) {
            int c = col0 + tx + 16 * j;
            store_out(&C[(size_t)r * N + c], acc[i][j] + bias[c]);
        }
    }
}

// ---------------------------------------------------------------------------
// Flash attention with MFMA (bf16 inputs, fp32 accumulate / softmax).
// Block = 256 threads = 4 waves. Each block: 64 query rows of one (b,h);
// wave w owns query rows [16w, 16w+16). K-tiles of 64 rows iterate up the
// causal range. QK^T and PV via mfma_f32_16x16x32_bf16.
//
// Layouts (verified gfx950 mappings):
//   A-frag:  A[m = lane&15][k = (lane>>4)*8 + j]   -> row-major LDS, b128 reads
//   B-frag:  B[k = (lane>>4)*8 + j][n = lane&15]   -> "row n holds its k-run"
//   C/D:     col = lane&15, row = (lane>>4)*4 + reg
// P exits QK in C/D layout, must re-enter PV in A layout -> LDS round-trip.
// V is transposed during staging so PV B-frags are contiguous b128 reads.
// LDS rows padded to stride 72 (144 B = 16*9): rows rotate banks, <=2-way.
// ---------------------------------------------------------------------------
#define BR 64
#define BC 64
#define LSTR 72

__global__ __launch_bounds__(256) void attn_mfma_kernel(
    const unsigned short* __restrict__ Qg, const unsigned short* __restrict__ Kg,
    const unsigned short* __restrict__ Vg, float* __restrict__ O)
{
    __shared__ unsigned short sQ[BR * LSTR];
    __shared__ unsigned short sK[BC * LSTR];
    __shared__ unsigned short sVt[DK * LSTR];   // sVt[dk][j]
    __shared__ unsigned short sP[BR * LSTR];    // wave-private row stripes

    const int t    = threadIdx.x;
    const int w    = t >> 6;        // wave id 0..3
    const int lane = t & 63;
    const int ln   = lane & 15;     // n / m index within 16x16 tile
    const int qg   = lane >> 4;     // quad group 0..3

    const int id  = blockIdx.x;     // 1024 blocks; bh fastest for causal balance
    const int bh  = id & 31;
    const int qt  = id >> 5;
    const int b   = bh >> 4;
    const int h   = bh & 15;
    const int qi0 = qt * BR;

    const size_t rowbase = (size_t)b * SEQ;
    const size_t colbase = (size_t)h * DK;

    // ---- stage Q tile (64x64 bf16) ----
#pragma unroll
    for (int it = 0; it < 2; ++it) {
        int chunk = t + 256 * it;       // 0..511
        int r = chunk >> 3;             // 0..63
        int c = (chunk & 7) * 8;        // 0..56
        *(uint4*)&sQ[r * LSTR + c] =
            *(const uint4*)&Qg[(rowbase + qi0 + r) * DMODEL + colbase + c];
    }

    f32x4 ofrag[4];                     // O stripe: 4 dk-chunks x 4 rows/lane
#pragma unroll
    for (int nt = 0; nt < 4; ++nt) ofrag[nt] = (f32x4){0.f, 0.f, 0.f, 0.f};
    float m_r[4], l_r[4];
#pragma unroll
    for (int r = 0; r < 4; ++r) { m_r[r] = -3.0e38f; l_r[r] = 0.f; }

    for (int j0 = 0; j0 <= qi0; j0 += BC) {
        __syncthreads();                // previous tile's LDS reads complete
        // ---- stage K tile (row-major) ----
#pragma unroll
        for (int it = 0; it < 2; ++it) {
            int chunk = t + 256 * it;
            int r = chunk >> 3;
            int c = (chunk & 7) * 8;
            *(uint4*)&sK[r * LSTR + c] =
                *(const uint4*)&Kg[(rowbase + j0 + r) * DMODEL + colbase + c];
        }
        // ---- stage V tile transposed: sVt[dk][j] = V[j][dk] ----
#pragma unroll
        for (int it = 0; it < 2; ++it) {
            int chunk = t + 256 * it;
            int r = chunk >> 3;             // v row j
            int c = (chunk & 7) * 8;        // dk col base
            union { uint4 u; unsigned short s[8]; } d;
            d.u = *(const uint4*)&Vg[(rowbase + j0 + r) * DMODEL + colbase + c];
#pragma unroll
            for (int u = 0; u < 8; ++u) sVt[(c + u) * LSTR + r] = d.s[u];
        }
        __syncthreads();

        // ---- S = Q K^T for this wave's 16-row stripe ----
        const unsigned short* qb = &sQ[(w * 16 + ln) * LSTR + qg * 8];
        bf16x8 aq0 = *(const bf16x8*)qb;
        bf16x8 aq1 = *(const bf16x8*)(qb + 32);

        f32x4 sf[4];
#pragma unroll
        for (int nt = 0; nt < 4; ++nt) {
            const unsigned short* kb = &sK[(nt * 16 + ln) * LSTR + qg * 8];
            bf16x8 bk0 = *(const bf16x8*)kb;
            bf16x8 bk1 = *(const bf16x8*)(kb + 32);
            f32x4 acc = (f32x4){0.f, 0.f, 0.f, 0.f};
            acc = __builtin_amdgcn_mfma_f32_16x16x32_bf16(aq0, bk0, acc, 0, 0, 0);
            acc = __builtin_amdgcn_mfma_f32_16x16x32_bf16(aq1, bk1, acc, 0, 0, 0);
            sf[nt] = acc;
        }

        // ---- scale + causal mask (only the diagonal tile is partial) ----
        const bool diag = (j0 == qi0);
#pragma unroll
        for (int nt = 0; nt < 4; ++nt)
#pragma unroll
            for (int r = 0; r < 4; ++r) {
                float x = sf[nt][r] * 0.125f;   // 1/sqrt(DK)
                if (diag) {
                    int qrow = w * 16 + qg * 4 + r;   // local q row
                    int col  = nt * 16 + ln;          // local k row
                    if (col > qrow) x = -3.0e38f;
                }
                sf[nt][r] = x;
            }

        // ---- online softmax: row stats across 16 lanes sharing qg ----
        float rmax[4];
#pragma unroll
        for (int r = 0; r < 4; ++r)
            rmax[r] = fmaxf(fmaxf(sf[0][r], sf[1][r]), fmaxf(sf[2][r], sf[3][r]));
#pragma unroll
        for (int off = 8; off >= 1; off >>= 1)
#pragma unroll
            for (int r = 0; r < 4; ++r)
                rmax[r] = fmaxf(rmax[r], __shfl_xor(rmax[r], off));

        float alpha[4];
#pragma unroll
        for (int r = 0; r < 4; ++r) {
            float mn = fmaxf(m_r[r], rmax[r]);
            alpha[r] = __expf(m_r[r] - mn);
            m_r[r] = mn;
        }

        float pf[4][4];
        float rsum[4] = {0.f, 0.f, 0.f, 0.f};
#pragma unroll
        for (int nt = 0; nt < 4; ++nt)
#pragma unroll
            for (int r = 0; r < 4; ++r) {
                float p = __expf(sf[nt][r] - m_r[r]);
                pf[nt][r] = p;
                rsum[r] += p;
            }
#pragma unroll
        for (int off = 8; off >= 1; off >>= 1)
#pragma unroll
            for (int r = 0; r < 4; ++r)
                rsum[r] += __shfl_xor(rsum[r], off);
#pragma unroll
        for (int r = 0; r < 4; ++r) l_r[r] = l_r[r] * alpha[r] + rsum[r];
#pragma unroll
        for (int nt = 0; nt < 4; ++nt)
#pragma unroll
            for (int r = 0; r < 4; ++r) ofrag[nt][r] *= alpha[r];

        // ---- P: C-layout regs -> LDS (wave-private stripe) -> A-layout ----
#pragma unroll
        for (int nt = 0; nt < 4; ++nt)
#pragma unroll
            for (int r = 0; r < 4; ++r)
                sP[(w * 16 + qg * 4 + r) * LSTR + nt * 16 + ln] = f2bf(pf[nt][r]);

        // ---- O += P V ----
        const unsigned short* pb = &sP[(w * 16 + ln) * LSTR + qg * 8];
        bf16x8 ap0 = *(const bf16x8*)pb;
        bf16x8 ap1 = *(const bf16x8*)(pb + 32);
#pragma unroll
        for (int nt = 0; nt < 4; ++nt) {
            const unsigned short* vb = &sVt[(nt * 16 + ln) * LSTR + qg * 8];
            bf16x8 bv0 = *(const bf16x8*)vb;
            bf16x8 bv1 = *(const bf16x8*)(vb + 32);
            ofrag[nt] = __builtin_amdgcn_mfma_f32_16x16x32_bf16(ap0, bv0, ofrag[nt], 0, 0, 0);
            ofrag[nt] = __builtin_amdgcn_mfma_f32_16x16x32_bf16(ap1, bv1, ofrag[nt], 0, 0, 0);
        }
    }

    // ---- epilogue: normalize, write fp32 ctx in [B,S,D] layout ----
#pragma unroll
    for (int nt = 0; nt < 4; ++nt)
#pragma unroll
        for (int r = 0; r < 4; ++r) {
            int gq = qi0 + w * 16 + qg * 4 + r;
            O[(rowbase + gq) * DMODEL + colbase + nt * 16 + ln] = ofrag[nt][r] / l_r[r];
        }
}

// ---------------------------------------------------------------------------
extern "C" void kernel_launch(void* const* d_in, const int* in_sizes, int n_in,
                              void* d_out, int out_size, void* d_ws, size_t ws_size,
                              hipStream_t stream)
{
    const float* q  = (const float*)d_in[0];
    const float* k  = (const float*)d_in[1];
    const float* v  = (const float*)d_in[2];
    // d_in[3] = mask (int32 tril) — causality applied analytically (j<=i).
    const float* wq = (const float*)d_in[4];
    const float* bq = (const float*)d_in[5];
    const float* wk = (const float*)d_in[6];
    const float* bk = (const float*)d_in[7];
    const float* wv = (const float*)d_in[8];
    const float* bv = (const float*)d_in[9];
    const float* wo = (const float*)d_in[10];
    const float* bo = (const float*)d_in[11];
    float* out = (float*)d_out;

    const size_t mat = (size_t)MTOK * DMODEL;       // elements per activation
    unsigned short* Qb = (unsigned short*)d_ws;     // bf16: 8 MB
    unsigned short* Kb = Qb + mat;                  // bf16: 8 MB
    unsigned short* Vb = Kb + mat;                  // bf16: 8 MB
    float* CTX = (float*)(Vb + mat);                // fp32: 16 MB (total 40 MB)

    dim3 blk(16, 16);
    dim3 grd(DMODEL / 64, MTOK / 64);               // (16, 64)

    gemm_bias_kernel<unsigned short><<<grd, blk, 0, stream>>>(q, wq, bq, Qb, MTOK, DMODEL, DMODEL);
    gemm_bias_kernel<unsigned short><<<grd, blk, 0, stream>>>(k, wk, bk, Kb, MTOK, DMODEL, DMODEL);
    gemm_bias_kernel<unsigned short><<<grd, blk, 0, stream>>>(v, wv, bv, Vb, MTOK, DMODEL, DMODEL);

    attn_mfma_kernel<<<BATCH * NHEAD * (SEQ / BR), 256, 0, stream>>>(Qb, Kb, Vb, CTX);

    gemm_bias_kernel<float><<<grd, blk, 0, stream>>>(CTX, wo, bo, out, MTOK, DMODEL, DMODEL);
}

// Round 3
// 344.023 us; speedup vs baseline: 9.6091x; 2.5035x over previous
//
#include <hip/hip_runtime.h>
#include <hip/hip_bf16.h>

// Problem constants (from reference)
#define BATCH 2
#define SEQ   2048
#define DMODEL 1024
#define NHEAD 16
#define DK    64
#define MTOK  (BATCH * SEQ)      // 4096 rows for the projection GEMMs

typedef __attribute__((ext_vector_type(8))) short bf16x8;   // 8 bf16 in 4 VGPRs
typedef __attribute__((ext_vector_type(4))) float f32x4;    // MFMA 16x16 accumulator

// float -> bf16 bits, round-to-nearest-even
__device__ __forceinline__ unsigned short f2bf(float x) {
    unsigned u = __float_as_uint(x);
    u = (u + 0x7FFFu + ((u >> 16) & 1u)) >> 16;
    return (unsigned short)u;
}

__device__ __forceinline__ void store_out(float* p, float v)          { *p = v; }
__device__ __forceinline__ void store_out(unsigned short* p, float v) { *p = f2bf(v); }

// async global->LDS, 16 B per lane; LDS dest = wave-uniform base + lane*16
__device__ __forceinline__ void g2lds16(const void* g, void* l) {
    __builtin_amdgcn_global_load_lds(
        (const __attribute__((address_space(1))) void*)g,
        (__attribute__((address_space(3))) void*)l, 16, 0, 0);
}

// ---------------------------------------------------------------------------
// fp32 -> bf16 elementwise convert (activations). n multiple of 2048.
// ---------------------------------------------------------------------------
__global__ __launch_bounds__(256) void cvt_bf16_kernel(
    const float* __restrict__ src, unsigned short* __restrict__ dst, int n)
{
    int i = (blockIdx.x * 256 + threadIdx.x) * 8;
    if (i >= n) return;
    float4 a = *(const float4*)(src + i);
    float4 b = *(const float4*)(src + i + 4);
    union { unsigned short s[8]; uint4 u; } o;
    o.s[0] = f2bf(a.x); o.s[1] = f2bf(a.y); o.s[2] = f2bf(a.z); o.s[3] = f2bf(a.w);
    o.s[4] = f2bf(b.x); o.s[5] = f2bf(b.y); o.s[6] = f2bf(b.z); o.s[7] = f2bf(b.w);
    *(uint4*)(dst + i) = o.u;
}

// ---------------------------------------------------------------------------
// Transpose + convert the 4 weight matrices: Wt[n][k] = (bf16)W[k][n], 1024^2.
// 32x32 tiles, LDS staged, blockIdx.z selects which weight.
// ---------------------------------------------------------------------------
__global__ __launch_bounds__(256) void wtrans_kernel(
    const float* __restrict__ w0, const float* __restrict__ w1,
    const float* __restrict__ w2, const float* __restrict__ w3,
    unsigned short* __restrict__ t0, unsigned short* __restrict__ t1,
    unsigned short* __restrict__ t2, unsigned short* __restrict__ t3)
{
    __shared__ float tile[32][33];
    const float* W; unsigned short* T;
    switch (blockIdx.z) {
        case 0:  W = w0; T = t0; break;
        case 1:  W = w1; T = t1; break;
        case 2:  W = w2; T = t2; break;
        default: W = w3; T = t3; break;
    }
    const int n0 = blockIdx.x * 32, k0 = blockIdx.y * 32;
    const int t  = threadIdx.x;
    const int r  = t >> 3;          // 0..31
    const int c4 = (t & 7) * 4;     // 0..28

    float4 v = *(const float4*)&W[(size_t)(k0 + r) * DMODEL + n0 + c4];
    tile[r][c4 + 0] = v.x; tile[r][c4 + 1] = v.y;
    tile[r][c4 + 2] = v.z; tile[r][c4 + 3] = v.w;
    __syncthreads();

    union { unsigned short s[4]; uint2 u; } o;
#pragma unroll
    for (int u = 0; u < 4; ++u) o.s[u] = f2bf(tile[c4 + u][r]);
    *(uint2*)&T[(size_t)(n0 + r) * DMODEL + k0 + c4] = o.u;
}

// ---------------------------------------------------------------------------
// bf16 MFMA GEMM: C[M,N] = A[M,K] @ Bt[N,K]^T + bias (fp32 acc).
// Tile 128x64, BK=64, 256 threads = 4 waves in 2x2, each wave 64x32 out.
// LDS is FRAGMENT-ORDERED: block bi holds one wave-fragment's 64 lanes x 16 B
// contiguously, so every ds_read_b128 is a conflict-free contiguous 1 KB read.
// global_load_lds gathers the per-lane source elements (per-lane vaddr is
// free; only the LDS base must be wave-uniform).
//   sA block bi = mtg*2+kc : lane holds A[row0+mtg*16+ln][kt*64+kc*32+qg*8 ..+8]
//   sB block bi = ntg*2+kc : lane holds Bt[col0+ntg*16+ln][kt*64+kc*32+qg*8 ..+8]
// ---------------------------------------------------------------------------
#define GBM 128
#define GBN 64
#define GBK 64

template <typename OutT>
__global__ __launch_bounds__(256) void gemm_mfma_kernel(
    const unsigned short* __restrict__ A, const unsigned short* __restrict__ Bt,
    const float* __restrict__ bias, OutT* __restrict__ C,
    int M, int N, int K)
{
    __shared__ unsigned short sA[16 * 512];   // 16 KB
    __shared__ unsigned short sB[8 * 512];    // 8 KB

    const int t    = threadIdx.x;
    const int w    = t >> 6;
    const int lane = t & 63;
    const int ln   = lane & 15;
    const int qg   = lane >> 4;
    const int wm   = w >> 1;     // 0..1 (which 64-row half)
    const int wn   = w & 1;      // 0..1 (which 32-col half)
    const int row0 = blockIdx.y * GBM;
    const int col0 = blockIdx.x * GBN;

    f32x4 acc[4][2];
#pragma unroll
    for (int mt = 0; mt < 4; ++mt)
#pragma unroll
        for (int nt = 0; nt < 2; ++nt) acc[mt][nt] = (f32x4){0.f, 0.f, 0.f, 0.f};

    for (int kt = 0; kt < K / GBK; ++kt) {
        __syncthreads();                         // previous iter's LDS reads done
        const int kbase = kt * GBK;
#pragma unroll
        for (int s6 = 0; s6 < 6; ++s6) {
            const int s = w * 6 + s6;            // wave-uniform, 0..23
            if (s < 16) {                        // A blocks
                const int mtg = s >> 1, kc = s & 1;
                const unsigned short* g =
                    A + (size_t)(row0 + mtg * 16 + ln) * K + kbase + kc * 32 + qg * 8;
                g2lds16(g, &sA[s * 512]);
            } else {                             // B blocks
                const int bi = s - 16;
                const int ntg = bi >> 1, kc = bi & 1;
                const unsigned short* g =
                    Bt + (size_t)(col0 + ntg * 16 + ln) * K + kbase + kc * 32 + qg * 8;
                g2lds16(g, &sB[bi * 512]);
            }
        }
        __syncthreads();                         // staging visible (vmcnt drained)

#pragma unroll
        for (int kc = 0; kc < 2; ++kc) {
            bf16x8 aF[4], bF[2];
#pragma unroll
            for (int mt = 0; mt < 4; ++mt)
                aF[mt] = *(const bf16x8*)&sA[(((wm * 4 + mt) * 2) + kc) * 512 + lane * 8];
#pragma unroll
            for (int nt = 0; nt < 2; ++nt)
                bF[nt] = *(const bf16x8*)&sB[(((wn * 2 + nt) * 2) + kc) * 512 + lane * 8];
#pragma unroll
            for (int mt = 0; mt < 4; ++mt)
#pragma unroll
                for (int nt = 0; nt < 2; ++nt)
                    acc[mt][nt] = __builtin_amdgcn_mfma_f32_16x16x32_bf16(
                        aF[mt], bF[nt], acc[mt][nt], 0, 0, 0);
        }
    }

    // epilogue: C/D layout col=ln, row=qg*4+r
#pragma unroll
    for (int mt = 0; mt < 4; ++mt)
#pragma unroll
        for (int nt = 0; nt < 2; ++nt)
#pragma unroll
            for (int r = 0; r < 4; ++r) {
                int row = row0 + wm * 64 + mt * 16 + qg * 4 + r;
                int col = col0 + wn * 32 + nt * 16 + ln;
                store_out(&C[(size_t)row * N + col], acc[mt][nt][r] + bias[col]);
            }
}

// ---------------------------------------------------------------------------
// Flash attention with MFMA (bf16 in, fp32 softmax/acc, bf16 out).
// Unchanged from round 2 except: CTX written as bf16; q-tile order reversed so
// heavy causal blocks dispatch first.
// ---------------------------------------------------------------------------
#define BR 64
#define BC 64
#define LSTR 72

__global__ __launch_bounds__(256) void attn_mfma_kernel(
    const unsigned short* __restrict__ Qg, const unsigned short* __restrict__ Kg,
    const unsigned short* __restrict__ Vg, unsigned short* __restrict__ O)
{
    __shared__ unsigned short sQ[BR * LSTR];
    __shared__ unsigned short sK[BC * LSTR];
    __shared__ unsigned short sVt[DK * LSTR];   // sVt[dk][j]
    __shared__ unsigned short sP[BR * LSTR];

    const int t    = threadIdx.x;
    const int w    = t >> 6;
    const int lane = t & 63;
    const int ln   = lane & 15;
    const int qg   = lane >> 4;

    const int id  = blockIdx.x;
    const int bh  = id & 31;
    const int qt  = (SEQ / BR - 1) - (id >> 5);   // heavy tiles first
    const int b   = bh >> 4;
    const int h   = bh & 15;
    const int qi0 = qt * BR;

    const size_t rowbase = (size_t)b * SEQ;
    const size_t colbase = (size_t)h * DK;

#pragma unroll
    for (int it = 0; it < 2; ++it) {
        int chunk = t + 256 * it;
        int r = chunk >> 3;
        int c = (chunk & 7) * 8;
        *(uint4*)&sQ[r * LSTR + c] =
            *(const uint4*)&Qg[(rowbase + qi0 + r) * DMODEL + colbase + c];
    }

    f32x4 ofrag[4];
#pragma unroll
    for (int nt = 0; nt < 4; ++nt) ofrag[nt] = (f32x4){0.f, 0.f, 0.f, 0.f};
    float m_r[4], l_r[4];
#pragma unroll
    for (int r = 0; r < 4; ++r) { m_r[r] = -3.0e38f; l_r[r] = 0.f; }

    for (int j0 = 0; j0 <= qi0; j0 += BC) {
        __syncthreads();
#pragma unroll
        for (int it = 0; it < 2; ++it) {
            int chunk = t + 256 * it;
            int r = chunk >> 3;
            int c = (chunk & 7) * 8;
            *(uint4*)&sK[r * LSTR + c] =
                *(const uint4*)&Kg[(rowbase + j0 + r) * DMODEL + colbase + c];
        }
#pragma unroll
        for (int it = 0; it < 2; ++it) {
            int chunk = t + 256 * it;
            int r = chunk >> 3;
            int c = (chunk & 7) * 8;
            union { uint4 u; unsigned short s[8]; } d;
            d.u = *(const uint4*)&Vg[(rowbase + j0 + r) * DMODEL + colbase + c];
#pragma unroll
            for (int u = 0; u < 8; ++u) sVt[(c + u) * LSTR + r] = d.s[u];
        }
        __syncthreads();

        const unsigned short* qb = &sQ[(w * 16 + ln) * LSTR + qg * 8];
        bf16x8 aq0 = *(const bf16x8*)qb;
        bf16x8 aq1 = *(const bf16x8*)(qb + 32);

        f32x4 sf[4];
#pragma unroll
        for (int nt = 0; nt < 4; ++nt) {
            const unsigned short* kb = &sK[(nt * 16 + ln) * LSTR + qg * 8];
            bf16x8 bk0 = *(const bf16x8*)kb;
            bf16x8 bk1 = *(const bf16x8*)(kb + 32);
            f32x4 a2 = (f32x4){0.f, 0.f, 0.f, 0.f};
            a2 = __builtin_amdgcn_mfma_f32_16x16x32_bf16(aq0, bk0, a2, 0, 0, 0);
            a2 = __builtin_amdgcn_mfma_f32_16x16x32_bf16(aq1, bk1, a2, 0, 0, 0);
            sf[nt] = a2;
        }

        const bool diag = (j0 == qi0);
#pragma unroll
        for (int nt = 0; nt < 4; ++nt)
#pragma unroll
            for (int r = 0; r < 4; ++r) {
                float x = sf[nt][r] * 0.125f;
                if (diag) {
                    int qrow = w * 16 + qg * 4 + r;
                    int col  = nt * 16 + ln;
                    if (col > qrow) x = -3.0e38f;
                }
                sf[nt][r] = x;
            }

        float rmax[4];
#pragma unroll
        for (int r = 0; r < 4; ++r)
            rmax[r] = fmaxf(fmaxf(sf[0][r], sf[1][r]), fmaxf(sf[2][r], sf[3][r]));
#pragma unroll
        for (int off = 8; off >= 1; off >>= 1)
#pragma unroll
            for (int r = 0; r < 4; ++r)
                rmax[r] = fmaxf(rmax[r], __shfl_xor(rmax[r], off));

        float alpha[4];
#pragma unroll
        for (int r = 0; r < 4; ++r) {
            float mn = fmaxf(m_r[r], rmax[r]);
            alpha[r] = __expf(m_r[r] - mn);
            m_r[r] = mn;
        }

        float pf[4][4];
        float rsum[4] = {0.f, 0.f, 0.f, 0.f};
#pragma unroll
        for (int nt = 0; nt < 4; ++nt)
#pragma unroll
            for (int r = 0; r < 4; ++r) {
                float p = __expf(sf[nt][r] - m_r[r]);
                pf[nt][r] = p;
                rsum[r] += p;
            }
#pragma unroll
        for (int off = 8; off >= 1; off >>= 1)
#pragma unroll
            for (int r = 0; r < 4; ++r)
                rsum[r] += __shfl_xor(rsum[r], off);
#pragma unroll
        for (int r = 0; r < 4; ++r) l_r[r] = l_r[r] * alpha[r] + rsum[r];
#pragma unroll
        for (int nt = 0; nt < 4; ++nt)
#pragma unroll
            for (int r = 0; r < 4; ++r) ofrag[nt][r] *= alpha[r];

#pragma unroll
        for (int nt = 0; nt < 4; ++nt)
#pragma unroll
            for (int r = 0; r < 4; ++r)
                sP[(w * 16 + qg * 4 + r) * LSTR + nt * 16 + ln] = f2bf(pf[nt][r]);

        const unsigned short* pb = &sP[(w * 16 + ln) * LSTR + qg * 8];
        bf16x8 ap0 = *(const bf16x8*)pb;
        bf16x8 ap1 = *(const bf16x8*)(pb + 32);
#pragma unroll
        for (int nt = 0; nt < 4; ++nt) {
            const unsigned short* vb = &sVt[(nt * 16 + ln) * LSTR + qg * 8];
            bf16x8 bv0 = *(const bf16x8*)vb;
            bf16x8 bv1 = *(const bf16x8*)(vb + 32);
            ofrag[nt] = __builtin_amdgcn_mfma_f32_16x16x32_bf16(ap0, bv0, ofrag[nt], 0, 0, 0);
            ofrag[nt] = __builtin_amdgcn_mfma_f32_16x16x32_bf16(ap1, bv1, ofrag[nt], 0, 0, 0);
        }
    }

#pragma unroll
    for (int nt = 0; nt < 4; ++nt)
#pragma unroll
        for (int r = 0; r < 4; ++r) {
            int gq = qi0 + w * 16 + qg * 4 + r;
            O[(rowbase + gq) * DMODEL + colbase + nt * 16 + ln] =
                f2bf(ofrag[nt][r] / l_r[r]);
        }
}

// ---------------------------------------------------------------------------
extern "C" void kernel_launch(void* const* d_in, const int* in_sizes, int n_in,
                              void* d_out, int out_size, void* d_ws, size_t ws_size,
                              hipStream_t stream)
{
    const float* q  = (const float*)d_in[0];
    const float* k  = (const float*)d_in[1];
    const float* v  = (const float*)d_in[2];
    // d_in[3] = mask (int32 tril) — causality applied analytically (j<=i).
    const float* wq = (const float*)d_in[4];
    const float* bq = (const float*)d_in[5];
    const float* wk = (const float*)d_in[6];
    const float* bk = (const float*)d_in[7];
    const float* wv = (const float*)d_in[8];
    const float* bv = (const float*)d_in[9];
    const float* wo = (const float*)d_in[10];
    const float* bo = (const float*)d_in[11];
    float* out = (float*)d_out;

    const size_t mat  = (size_t)MTOK * DMODEL;     // 4M elements
    const size_t wmat = (size_t)DMODEL * DMODEL;   // 1M elements
    unsigned short* Abq = (unsigned short*)d_ws;   // bf16 activations
    unsigned short* Abk = Abq + mat;
    unsigned short* Abv = Abk + mat;
    unsigned short* WtQ = Abv + mat;               // bf16 transposed weights
    unsigned short* WtK = WtQ + wmat;
    unsigned short* WtV = WtK + wmat;
    unsigned short* WtO = WtV + wmat;
    unsigned short* Qb  = WtO + wmat;              // bf16 projections
    unsigned short* Kb  = Qb + mat;
    unsigned short* Vb  = Kb + mat;
    unsigned short* CTX = Vb + mat;                // bf16 attention output
    // total: 7*mat + 4*wmat = 32M elems = 64 MB

    const int cvtgrid = (int)(mat / (256 * 8));    // 2048
    cvt_bf16_kernel<<<cvtgrid, 256, 0, stream>>>(q, Abq, (int)mat);
    cvt_bf16_kernel<<<cvtgrid, 256, 0, stream>>>(k, Abk, (int)mat);
    cvt_bf16_kernel<<<cvtgrid, 256, 0, stream>>>(v, Abv, (int)mat);
    wtrans_kernel<<<dim3(32, 32, 4), 256, 0, stream>>>(wq, wk, wv, wo, WtQ, WtK, WtV, WtO);

    dim3 ggrid(DMODEL / GBN, MTOK / GBM);          // (16, 32)
    gemm_mfma_kernel<unsigned short><<<ggrid, 256, 0, stream>>>(Abq, WtQ, bq, Qb, MTOK, DMODEL, DMODEL);
    gemm_mfma_kernel<unsigned short><<<ggrid, 256, 0, stream>>>(Abk, WtK, bk, Kb, MTOK, DMODEL, DMODEL);
    gemm_mfma_kernel<unsigned short><<<ggrid, 256, 0, stream>>>(Abv, WtV, bv, Vb, MTOK, DMODEL, DMODEL);

    attn_mfma_kernel<<<BATCH * NHEAD * (SEQ / BR), 256, 0, stream>>>(Qb, Kb, Vb, CTX);

    gemm_mfma_kernel<float><<<ggrid, 256, 0, stream>>>(CTX, WtO, bo, out, MTOK, DMODEL, DMODEL);
}